// Round 1
// baseline (228.173 us; speedup 1.0000x reference)
//
#include <hip/hip_runtime.h>
#include <hip/hip_bf16.h>

// Problem: out[b,o] = sum_i inputs[b,i] * mean[indices[i,o]] + bias[o]
// B=2048, IN=4096, OUT=4096.  inputs f32, indices i32, mean f32, bias f32, out f32.

#define M_DIM 2048
#define K_DIM 4096
#define N_DIM 4096

typedef __attribute__((ext_vector_type(8))) short short8v;
typedef __attribute__((ext_vector_type(4))) float f32x4;

__device__ __forceinline__ unsigned short f2bf(float x) {
    unsigned u = __builtin_bit_cast(unsigned, x);
    u += 0x7fffu + ((u >> 16) & 1u);   // round-to-nearest-even
    return (unsigned short)(u >> 16);
}

__device__ __forceinline__ void gload_lds16(const void* g, void* l) {
    __builtin_amdgcn_global_load_lds(
        (const __attribute__((address_space(1))) void*)(uintptr_t)g,
        (__attribute__((address_space(3))) void*)(uintptr_t)l, 16, 0, 0);
}

// ---------------- Kernel 1: A f32 -> bf16 (row-major unchanged) ----------------
__global__ void convert_a_kernel(const float* __restrict__ A,
                                 unsigned short* __restrict__ Abf) {
    int i = blockIdx.x * blockDim.x + threadIdx.x;   // one float4 per thread
    const float4 v = ((const float4*)A)[i];
    ushort4 o;
    o.x = f2bf(v.x); o.y = f2bf(v.y); o.z = f2bf(v.z); o.w = f2bf(v.w);
    ((ushort4*)Abf)[i] = o;
}

// ------------- Kernel 2: decode + transpose: Wt[n][k] = bf16(mean[indices[k][n]]) -------------
__global__ void decode_transpose_kernel(const int* __restrict__ idx,
                                        const float* __restrict__ mean,
                                        unsigned short* __restrict__ Wt) {
    __shared__ float smean[K_DIM];
    __shared__ unsigned short tile[64][65];   // [n-local][k-local], +1 pad
    const int t = threadIdx.x;                // 0..255
    for (int i = t; i < K_DIM; i += 256) smean[i] = mean[i];
    __syncthreads();

    const int k0 = blockIdx.y * 64;           // row block in indices (k / in_dim)
    const int n0 = blockIdx.x * 64;           // col block (n / out_dim)
    const int rb = t >> 4;                    // 0..15
    const int cb = (t & 15) * 4;              // 0..60

    #pragma unroll
    for (int i = 0; i < 4; ++i) {
        const int r = rb + i * 16;            // k-local
        const int4 v = *(const int4*)&idx[(size_t)(k0 + r) * N_DIM + n0 + cb];
        tile[cb + 0][r] = f2bf(smean[v.x]);
        tile[cb + 1][r] = f2bf(smean[v.y]);
        tile[cb + 2][r] = f2bf(smean[v.z]);
        tile[cb + 3][r] = f2bf(smean[v.w]);
    }
    __syncthreads();

    #pragma unroll
    for (int i = 0; i < 4; ++i) {
        const int r = rb + i * 16;            // n-local
        ushort4 o;
        o.x = tile[r][cb + 0];
        o.y = tile[r][cb + 1];
        o.z = tile[r][cb + 2];
        o.w = tile[r][cb + 3];
        *(ushort4*)&Wt[(size_t)(n0 + r) * K_DIM + k0 + cb] = o;
    }
}

// ---------------- Kernel 3: bf16 GEMM  C = Abf @ Wt^T + bias ----------------
// m97 structure: 128x128 tile, BK=32, 4 waves (2x2), 4x4 16x16x32 frags/wave,
// global_load_lds width=16 staging, linear LDS.
__global__ void gemm_kernel(const unsigned short* __restrict__ Abf,   // [M][K]
                            const unsigned short* __restrict__ Wt,    // [N][K]
                            const float* __restrict__ bias,           // [N]
                            float* __restrict__ C) {                  // [M][N]
    __shared__ unsigned short sA[128 * 32];   // [m-local][k-local] 8 KiB
    __shared__ unsigned short sB[128 * 32];   // [n-local][k-local] 8 KiB

    const int tid  = threadIdx.x;             // 0..255
    const int lane = tid & 63;
    const int w    = tid >> 6;                // wave 0..3
    const int wm   = w >> 1, wn = w & 1;      // 2x2 wave grid
    const int m0   = blockIdx.y * 128;
    const int n0   = blockIdx.x * 128;

    f32x4 acc[4][4] = {};

    // staging assignment: chunk = tid (rows 0..63) and 256+tid (rows 64..127)
    const int r0   = tid >> 2;                // 0..63
    const int sub0 = (tid & 3) * 16;          // byte offset within 64B row

    const int lr = lane & 15;                 // row/col within fragment
    const int kq = lane >> 4;                 // k-quadrant (8 bf16 each)

    for (int k0 = 0; k0 < K_DIM; k0 += 32) {
        // ---- stage A tile (128x32) and B tile (128x32), linear LDS ----
        const char* gA0 = (const char*)(Abf + (size_t)(m0 + r0) * K_DIM + k0) + sub0;
        const char* gA1 = (const char*)(Abf + (size_t)(m0 + 64 + r0) * K_DIM + k0) + sub0;
        const char* gB0 = (const char*)(Wt  + (size_t)(n0 + r0) * K_DIM + k0) + sub0;
        const char* gB1 = (const char*)(Wt  + (size_t)(n0 + 64 + r0) * K_DIM + k0) + sub0;
        gload_lds16(gA0, (char*)sA + tid * 16);
        gload_lds16(gA1, (char*)sA + 4096 + tid * 16);
        gload_lds16(gB0, (char*)sB + tid * 16);
        gload_lds16(gB1, (char*)sB + 4096 + tid * 16);
        __syncthreads();   // compiler emits vmcnt(0) drain before s_barrier

        // ---- fragments + MFMA ----
        short8v a[4], b[4];
        #pragma unroll
        for (int i = 0; i < 4; ++i) {
            a[i] = *(const short8v*)&sA[(wm * 64 + i * 16 + lr) * 32 + kq * 8];
            b[i] = *(const short8v*)&sB[(wn * 64 + i * 16 + lr) * 32 + kq * 8];
        }
        #pragma unroll
        for (int i = 0; i < 4; ++i)
            #pragma unroll
            for (int j = 0; j < 4; ++j)
                acc[i][j] = __builtin_amdgcn_mfma_f32_16x16x32_bf16(a[i], b[j], acc[i][j], 0, 0, 0);
        __syncthreads();
    }

    // ---- epilogue: C[m][n] = acc + bias[n] ----
    #pragma unroll
    for (int j = 0; j < 4; ++j) {
        const int n = n0 + wn * 64 + j * 16 + lr;
        const float bv = bias[n];
        #pragma unroll
        for (int i = 0; i < 4; ++i) {
            const int mb = m0 + wm * 64 + i * 16 + kq * 4;
            #pragma unroll
            for (int q = 0; q < 4; ++q)
                C[(size_t)(mb + q) * N_DIM + n] = acc[i][j][q] + bv;
        }
    }
}

extern "C" void kernel_launch(void* const* d_in, const int* in_sizes, int n_in,
                              void* d_out, int out_size, void* d_ws, size_t ws_size,
                              hipStream_t stream) {
    const float* inputs  = (const float*)d_in[0];   // (2048, 4096) f32
    const int*   indices = (const int*)  d_in[1];   // (4096, 4096) i32
    const float* mean    = (const float*)d_in[2];   // (4096,) f32
    const float* bias    = (const float*)d_in[3];   // (4096,) f32
    float* out = (float*)d_out;                     // (2048, 4096) f32

    unsigned short* Abf = (unsigned short*)d_ws;                                   // 16 MiB
    unsigned short* Wt  = (unsigned short*)((char*)d_ws + (size_t)M_DIM * K_DIM * 2); // 32 MiB

    // 1) A -> bf16
    convert_a_kernel<<<(M_DIM * K_DIM / 4) / 256, 256, 0, stream>>>(inputs, Abf);
    // 2) decode + transpose W
    decode_transpose_kernel<<<dim3(N_DIM / 64, K_DIM / 64), 256, 0, stream>>>(indices, mean, Wt);
    // 3) GEMM + bias
    gemm_kernel<<<dim3(N_DIM / 128, M_DIM / 128), 256, 0, stream>>>(Abf, Wt, bias, out);
}

// Round 2
// 209.774 us; speedup vs baseline: 1.0877x; 1.0877x over previous
//
#include <hip/hip_runtime.h>
#include <hip/hip_bf16.h>

// Problem: out[b,o] = sum_i inputs[b,i] * mean[indices[i,o]] + bias[o]
// B=2048, IN=4096, OUT=4096.  inputs f32, indices i32, mean f32, bias f32, out f32.

#define M_DIM 2048
#define K_DIM 4096
#define N_DIM 4096

#define BM 128
#define BN 256
#define BK 64
#define NT (K_DIM / BK)                       // 64 K-tiles
#define LDSA_BYTES (BM * BK * 2)              // 16384
#define LDSB_BYTES (BN * BK * 2)              // 32768
#define LDS_TILE   (LDSA_BYTES + LDSB_BYTES)  // 49152

typedef __attribute__((ext_vector_type(8))) short short8v;
typedef __attribute__((ext_vector_type(4))) float f32x4;

__device__ __forceinline__ unsigned short f2bf(float x) {
    unsigned u = __builtin_bit_cast(unsigned, x);
    u += 0x7fffu + ((u >> 16) & 1u);   // round-to-nearest-even
    return (unsigned short)(u >> 16);
}

__device__ __forceinline__ void gload_lds16(const void* g, void* l) {
    __builtin_amdgcn_global_load_lds(
        (const __attribute__((address_space(1))) void*)(uintptr_t)g,
        (__attribute__((address_space(3))) void*)(uintptr_t)l, 16, 0, 0);
}

// ---------------- Kernel 1: A f32 -> bf16 ----------------
__global__ void convert_a_kernel(const float* __restrict__ A,
                                 unsigned short* __restrict__ Abf) {
    int i = blockIdx.x * blockDim.x + threadIdx.x;
    const float4 v = ((const float4*)A)[i];
    ushort4 o;
    o.x = f2bf(v.x); o.y = f2bf(v.y); o.z = f2bf(v.z); o.w = f2bf(v.w);
    ((ushort4*)Abf)[i] = o;
}

// ------------- Kernel 2: decode + transpose: Wt[n][k] = bf16(mean[indices[k][n]]) -------------
__global__ void decode_transpose_kernel(const int* __restrict__ idx,
                                        const float* __restrict__ mean,
                                        unsigned short* __restrict__ Wt) {
    __shared__ float smean[K_DIM];
    __shared__ unsigned short tile[64][65];
    const int t = threadIdx.x;
    for (int i = t; i < K_DIM; i += 256) smean[i] = mean[i];
    __syncthreads();

    const int k0 = blockIdx.y * 64;
    const int n0 = blockIdx.x * 64;
    const int rb = t >> 4;
    const int cb = (t & 15) * 4;

    #pragma unroll
    for (int i = 0; i < 4; ++i) {
        const int r = rb + i * 16;
        const int4 v = *(const int4*)&idx[(size_t)(k0 + r) * N_DIM + n0 + cb];
        tile[cb + 0][r] = f2bf(smean[v.x]);
        tile[cb + 1][r] = f2bf(smean[v.y]);
        tile[cb + 2][r] = f2bf(smean[v.z]);
        tile[cb + 3][r] = f2bf(smean[v.w]);
    }
    __syncthreads();

    #pragma unroll
    for (int i = 0; i < 4; ++i) {
        const int r = rb + i * 16;
        ushort4 o;
        o.x = tile[r][cb + 0];
        o.y = tile[r][cb + 1];
        o.z = tile[r][cb + 2];
        o.w = tile[r][cb + 3];
        *(ushort4*)&Wt[(size_t)(n0 + r) * K_DIM + k0 + cb] = o;
    }
}

// ---------------- Kernel 3: bf16 GEMM  C = Abf @ Wt^T + bias ----------------
// Phase-split pipelined structure (T2+T3+T4+T5):
//  - BM=128 x BN=256, BK=64, 8 waves (2Mx4N), per-wave 64x64 (4x4 frags).
//  - Triple-buffered LDS (3 x 48 KiB), prefetch distance 2 K-tiles.
//  - 6 global_load_lds (16B) per thread per K-tile; s_waitcnt vmcnt(6) once
//    per K-tile BEFORE the barrier => tile t+1 guaranteed landed, tile t+2
//    stays in flight across barriers (counted vmcnt, never drain-0 in loop).
//  - T2 swizzle: 16B chunk c stored at c^(row&7); applied on the pre-swizzled
//    GLOBAL source (linear LDS dest for global_load_lds), undone on ds_read.
//  - 2 phases per K-tile (kk=0/1): 8x ds_read_b128 + 3x stage -> barrier ->
//    setprio(1) + 16 MFMA + setprio(0) -> [vmcnt] -> barrier.

#define VM6 asm volatile("s_waitcnt vmcnt(6)" ::: "memory")
#define VM0 asm volatile("s_waitcnt vmcnt(0)" ::: "memory")
#define NOPST ((void)0)

#define STG_FIRST(kst) do {                          \
    gload_lds16(srcA0 + (kst), pb2 + ldsA0);         \
    gload_lds16(srcA1 + (kst), pb2 + ldsA1);         \
    gload_lds16(srcB0 + (kst), pb2 + ldsB0);         \
} while (0)

#define STG_SECOND(kst) do {                         \
    gload_lds16(srcB1 + (kst), pb2 + ldsB1);         \
    gload_lds16(srcB2 + (kst), pb2 + ldsB2);         \
    gload_lds16(srcB3 + (kst), pb2 + ldsB3);         \
} while (0)

#define PHASE(kk, STAGES, ENDW) do {                                          \
    const int sc = ((((kk) * 4) + kq) ^ (lr & 7)) * 16;                       \
    short8v a0 = *(const short8v*)(pb0 + rA0 + sc);                           \
    short8v a1 = *(const short8v*)(pb0 + rA1 + sc);                           \
    short8v a2 = *(const short8v*)(pb0 + rA2 + sc);                           \
    short8v a3 = *(const short8v*)(pb0 + rA3 + sc);                           \
    short8v b0 = *(const short8v*)(pb0 + rB0 + sc);                           \
    short8v b1 = *(const short8v*)(pb0 + rB1 + sc);                           \
    short8v b2 = *(const short8v*)(pb0 + rB2 + sc);                           \
    short8v b3 = *(const short8v*)(pb0 + rB3 + sc);                           \
    STAGES;                                                                   \
    __builtin_amdgcn_s_barrier();                                             \
    __builtin_amdgcn_s_setprio(1);                                            \
    acc[0][0] = __builtin_amdgcn_mfma_f32_16x16x32_bf16(a0, b0, acc[0][0], 0, 0, 0); \
    acc[0][1] = __builtin_amdgcn_mfma_f32_16x16x32_bf16(a0, b1, acc[0][1], 0, 0, 0); \
    acc[0][2] = __builtin_amdgcn_mfma_f32_16x16x32_bf16(a0, b2, acc[0][2], 0, 0, 0); \
    acc[0][3] = __builtin_amdgcn_mfma_f32_16x16x32_bf16(a0, b3, acc[0][3], 0, 0, 0); \
    acc[1][0] = __builtin_amdgcn_mfma_f32_16x16x32_bf16(a1, b0, acc[1][0], 0, 0, 0); \
    acc[1][1] = __builtin_amdgcn_mfma_f32_16x16x32_bf16(a1, b1, acc[1][1], 0, 0, 0); \
    acc[1][2] = __builtin_amdgcn_mfma_f32_16x16x32_bf16(a1, b2, acc[1][2], 0, 0, 0); \
    acc[1][3] = __builtin_amdgcn_mfma_f32_16x16x32_bf16(a1, b3, acc[1][3], 0, 0, 0); \
    acc[2][0] = __builtin_amdgcn_mfma_f32_16x16x32_bf16(a2, b0, acc[2][0], 0, 0, 0); \
    acc[2][1] = __builtin_amdgcn_mfma_f32_16x16x32_bf16(a2, b1, acc[2][1], 0, 0, 0); \
    acc[2][2] = __builtin_amdgcn_mfma_f32_16x16x32_bf16(a2, b2, acc[2][2], 0, 0, 0); \
    acc[2][3] = __builtin_amdgcn_mfma_f32_16x16x32_bf16(a2, b3, acc[2][3], 0, 0, 0); \
    acc[3][0] = __builtin_amdgcn_mfma_f32_16x16x32_bf16(a3, b0, acc[3][0], 0, 0, 0); \
    acc[3][1] = __builtin_amdgcn_mfma_f32_16x16x32_bf16(a3, b1, acc[3][1], 0, 0, 0); \
    acc[3][2] = __builtin_amdgcn_mfma_f32_16x16x32_bf16(a3, b2, acc[3][2], 0, 0, 0); \
    acc[3][3] = __builtin_amdgcn_mfma_f32_16x16x32_bf16(a3, b3, acc[3][3], 0, 0, 0); \
    __builtin_amdgcn_s_setprio(0);                                            \
    ENDW;                                                                     \
    __builtin_amdgcn_s_barrier();                                             \
    __builtin_amdgcn_sched_barrier(0);                                        \
} while (0)

__global__ __launch_bounds__(512, 2) void gemm_kernel(
        const unsigned short* __restrict__ Abf,   // [M][K]
        const unsigned short* __restrict__ Wt,    // [N][K]
        const float* __restrict__ bias,           // [N]
        float* __restrict__ C) {                  // [M][N]
    __shared__ __align__(128) char lds[3 * LDS_TILE];   // 144 KiB

    const int tid  = threadIdx.x;                 // 0..511
    const int lane = tid & 63;
    const int w    = tid >> 6;                    // 0..7
    const int wm   = w >> 2;                      // 0..1
    const int wn   = w & 3;                       // 0..3
    const int lr   = lane & 15;
    const int kq   = lane >> 4;                   // 0..3

    // XCD-chunked bijective block swizzle (256 blocks, 8 XCDs, 32/XCD)
    const int bid = blockIdx.x;
    const int wg  = (bid & 7) * 32 + (bid >> 3);
    const int m0  = (wg >> 4) * BM;               // 16 M-blocks
    const int n0  = (wg & 15) * BN;               // 16 N-blocks

    // ---- staging descriptors: chunk p -> row=p>>3, swz chunk c=(p&7)^(row&7)
    const int pA0 = tid,        pA1 = 512 + tid;
    const int pB0 = tid,        pB1 = 512 + tid;
    const int pB2 = 1024 + tid, pB3 = 1536 + tid;
    const unsigned short* srcA0 = Abf + (size_t)(m0 + (pA0 >> 3)) * K_DIM + 8 * ((pA0 & 7) ^ ((pA0 >> 3) & 7));
    const unsigned short* srcA1 = Abf + (size_t)(m0 + (pA1 >> 3)) * K_DIM + 8 * ((pA1 & 7) ^ ((pA1 >> 3) & 7));
    const unsigned short* srcB0 = Wt  + (size_t)(n0 + (pB0 >> 3)) * K_DIM + 8 * ((pB0 & 7) ^ ((pB0 >> 3) & 7));
    const unsigned short* srcB1 = Wt  + (size_t)(n0 + (pB1 >> 3)) * K_DIM + 8 * ((pB1 & 7) ^ ((pB1 >> 3) & 7));
    const unsigned short* srcB2 = Wt  + (size_t)(n0 + (pB2 >> 3)) * K_DIM + 8 * ((pB2 & 7) ^ ((pB2 >> 3) & 7));
    const unsigned short* srcB3 = Wt  + (size_t)(n0 + (pB3 >> 3)) * K_DIM + 8 * ((pB3 & 7) ^ ((pB3 >> 3) & 7));
    const int ldsA0 = pA0 * 16, ldsA1 = pA1 * 16;
    const int ldsB0 = LDSA_BYTES + pB0 * 16, ldsB1 = LDSA_BYTES + pB1 * 16;
    const int ldsB2 = LDSA_BYTES + pB2 * 16, ldsB3 = LDSA_BYTES + pB3 * 16;

    // ---- fragment read row offsets (swizzle column added per-phase via sc)
    const int rA0 = (wm * 64 +  0 + lr) * 128;
    const int rA1 = (wm * 64 + 16 + lr) * 128;
    const int rA2 = (wm * 64 + 32 + lr) * 128;
    const int rA3 = (wm * 64 + 48 + lr) * 128;
    const int rB0 = LDSA_BYTES + (wn * 64 +  0 + lr) * 128;
    const int rB1 = LDSA_BYTES + (wn * 64 + 16 + lr) * 128;
    const int rB2 = LDSA_BYTES + (wn * 64 + 32 + lr) * 128;
    const int rB3 = LDSA_BYTES + (wn * 64 + 48 + lr) * 128;

    char* pb0 = (char*)lds;                 // compute buffer (tile t)
    char* pb1 = (char*)lds + LDS_TILE;      // tile t+1 (in flight / landed)
    char* pb2 = (char*)lds + 2 * LDS_TILE;  // stage target (tile t+2)

    f32x4 acc[4][4] = {};

    // ---- prologue: stage tiles 0 and 1 (oldest-first), wait tile 0 ----
    gload_lds16(srcA0 + 0, pb0 + ldsA0);
    gload_lds16(srcA1 + 0, pb0 + ldsA1);
    gload_lds16(srcB0 + 0, pb0 + ldsB0);
    gload_lds16(srcB1 + 0, pb0 + ldsB1);
    gload_lds16(srcB2 + 0, pb0 + ldsB2);
    gload_lds16(srcB3 + 0, pb0 + ldsB3);
    gload_lds16(srcA0 + BK, pb1 + ldsA0);
    gload_lds16(srcA1 + BK, pb1 + ldsA1);
    gload_lds16(srcB0 + BK, pb1 + ldsB0);
    gload_lds16(srcB1 + BK, pb1 + ldsB1);
    gload_lds16(srcB2 + BK, pb1 + ldsB2);
    gload_lds16(srcB3 + BK, pb1 + ldsB3);
    VM6;                                    // tile 0 landed; tile 1 in flight
    __builtin_amdgcn_s_barrier();

    // ---- main loop: compute tile t, stage tile t+2, wait vmcnt(6) ----
    for (int t = 0; t < NT - 2; ++t) {
        const int kst = (t + 2) * BK;
        PHASE(0, STG_FIRST(kst), NOPST);
        PHASE(1, STG_SECOND(kst), VM6);
        char* tmp = pb0; pb0 = pb1; pb1 = pb2; pb2 = tmp;
    }
    // tile NT-2: no staging; drain for the last tile
    PHASE(0, NOPST, NOPST);
    PHASE(1, NOPST, VM0);
    pb0 = pb1;
    // tile NT-1
    PHASE(0, NOPST, NOPST);
    PHASE(1, NOPST, NOPST);

    // ---- epilogue: C[m][n] = acc + bias[n] ----
    #pragma unroll
    for (int j = 0; j < 4; ++j) {
        const int n = n0 + wn * 64 + j * 16 + lr;
        const float bv = bias[n];
        #pragma unroll
        for (int i = 0; i < 4; ++i) {
            const int mb = m0 + wm * 64 + i * 16 + kq * 4;
            #pragma unroll
            for (int q = 0; q < 4; ++q)
                C[(size_t)(mb + q) * N_DIM + n] = acc[i][j][q] + bv;
        }
    }
}

extern "C" void kernel_launch(void* const* d_in, const int* in_sizes, int n_in,
                              void* d_out, int out_size, void* d_ws, size_t ws_size,
                              hipStream_t stream) {
    const float* inputs  = (const float*)d_in[0];   // (2048, 4096) f32
    const int*   indices = (const int*)  d_in[1];   // (4096, 4096) i32
    const float* mean    = (const float*)d_in[2];   // (4096,) f32
    const float* bias    = (const float*)d_in[3];   // (4096,) f32
    float* out = (float*)d_out;                     // (2048, 4096) f32

    unsigned short* Abf = (unsigned short*)d_ws;                                      // 16 MiB
    unsigned short* Wt  = (unsigned short*)((char*)d_ws + (size_t)M_DIM * K_DIM * 2); // 32 MiB

    convert_a_kernel<<<(M_DIM * K_DIM / 4) / 256, 256, 0, stream>>>(inputs, Abf);
    decode_transpose_kernel<<<dim3(N_DIM / 64, K_DIM / 64), 256, 0, stream>>>(indices, mean, Wt);
    gemm_kernel<<<256, 512, 0, stream>>>(Abf, Wt, bias, out);
}